// Round 3
// baseline (353.519 us; speedup 1.0000x reference)
//
#include <hip/hip_runtime.h>
#include <hip/hip_bf16.h>
#include <math.h>

using bf16 = __hip_bfloat16;
typedef __attribute__((ext_vector_type(8))) short short8;
typedef __attribute__((ext_vector_type(4))) float f32x4;
typedef __attribute__((ext_vector_type(4))) unsigned int u32x4;

#define BATCH 8192
#define SDIM  70
#define NS    64
#define NW    6
#define HID   1024
#define NA    4096
#define KPAD  96   // states K padded 70 -> 96 (multiple of 32)

// async global->LDS, 16 B per lane. LDS dest is wave-uniform base + lane*16.
__device__ __forceinline__ void gld_lds16(const bf16* g, bf16* l) {
    __builtin_amdgcn_global_load_lds(
        (const __attribute__((address_space(1))) void*)g,
        (__attribute__((address_space(3))) void*)l, 16, 0, 0);
}

// ---------------- conversion kernels ----------------

__global__ __launch_bounds__(256)
void cvt_states_k(const float* __restrict__ s, bf16* __restrict__ o) {
    int idx = blockIdx.x * 256 + threadIdx.x;          // BATCH*KPAD total
    int row = idx / KPAD;
    int col = idx - row * KPAD;
    float v = (col < SDIM) ? s[row * SDIM + col] : 0.0f;
    o[idx] = __float2bfloat16(v);
}

// fp32 [K][N] -> bf16 [N][Kpad] transposed, zero-pad k in [K,Kpad)
__global__ __launch_bounds__(256)
void transpose_cvt_k(const float* __restrict__ in, bf16* __restrict__ out,
                     int K, int N, int Kpad) {
    __shared__ float tile[32][33];
    int kb = blockIdx.y * 32, nb = blockIdx.x * 32;
    int tx = threadIdx.x, ty = threadIdx.y;
    #pragma unroll
    for (int i = 0; i < 32; i += 8) {
        int k = kb + ty + i, n = nb + tx;
        tile[ty + i][tx] = (k < K) ? in[(size_t)k * N + n] : 0.0f;
    }
    __syncthreads();
    #pragma unroll
    for (int i = 0; i < 32; i += 8) {
        int n = nb + ty + i, k = kb + tx;
        if (k < Kpad) out[(size_t)n * Kpad + k] = __float2bfloat16(tile[tx][ty + i]);
    }
}

// pack action columns: 6 fields x 5 bits
__global__ __launch_bounds__(256)
void pack_act_k(const int* __restrict__ act, unsigned* __restrict__ pact) {
    int c = blockIdx.x * 256 + threadIdx.x;
    if (c < NA) {
        const int* a = act + c * 6;
        unsigned p = 0;
        #pragma unroll
        for (int i = 0; i < 6; i++) p |= ((unsigned)a[i]) << (5 * i);
        pact[c] = p;
    }
}

// ---------------- bf16 MFMA GEMM, m97 structure ----------------
// C[M][N] = epilogue(A[M][K] @ BT[N][K]^T + bias)
// MODE 0: tanh -> bf16; MODE 1: raw -> fp32; MODE 2: raw -> bf16
// 256 threads = 4 waves; tile 128x128, BK=32; each wave computes 64x64.
template<int MODE>
__global__ __launch_bounds__(256)
void gemm128(const bf16* __restrict__ A, const bf16* __restrict__ BT,
             const float* __restrict__ bias, void* __restrict__ Cout,
             int M, int N, int K) {
    const int n0 = blockIdx.x * 128;
    const int m0 = blockIdx.y * 128;
    const int tid  = threadIdx.x;
    const int wave = tid >> 6;
    const int lane = tid & 63;

    __shared__ __align__(16) bf16 As[128 * 32];  // row-major, rowstride 32 (64 B), no pad
    __shared__ __align__(16) bf16 Bs[128 * 32];

    // staging: wave w covers rows [32w, 32w+32); lane i -> row 32w+(i>>2), k (i&3)*8
    const int srow = wave * 32 + (lane >> 2);
    const int sk   = (lane & 3) * 8;
    const bf16* ag = A  + (size_t)(m0 + srow) * K + sk;
    const bf16* bg = BT + (size_t)(n0 + srow) * K + sk;
    bf16* asl = &As[(wave * 32) * 32];          // wave-uniform LDS base
    bf16* bsl = &Bs[(wave * 32) * 32];

    f32x4 acc[4][4];
    #pragma unroll
    for (int i = 0; i < 4; i++)
        #pragma unroll
        for (int j = 0; j < 4; j++) acc[i][j] = (f32x4){0.f, 0.f, 0.f, 0.f};

    const int rb = (wave >> 1) * 64;   // wave's m block within tile
    const int cb = (wave & 1) * 64;    // wave's n block within tile
    const int fr = lane & 15;
    const int koff = (lane >> 4) * 8;

    for (int k0 = 0; k0 < K; k0 += 32) {
        gld_lds16(ag + k0,          asl);
        gld_lds16(ag + k0 + 16 * K, asl + 16 * 32);
        gld_lds16(bg + k0,          bsl);
        gld_lds16(bg + k0 + 16 * K, bsl + 16 * 32);
        __syncthreads();

        short8 af[4], bf[4];
        #pragma unroll
        for (int i = 0; i < 4; i++)
            af[i] = *(const short8*)&As[(rb + i * 16 + fr) * 32 + koff];
        #pragma unroll
        for (int j = 0; j < 4; j++)
            bf[j] = *(const short8*)&Bs[(cb + j * 16 + fr) * 32 + koff];
        #pragma unroll
        for (int i = 0; i < 4; i++)
            #pragma unroll
            for (int j = 0; j < 4; j++)
                acc[i][j] = __builtin_amdgcn_mfma_f32_16x16x32_bf16(af[i], bf[j], acc[i][j], 0, 0, 0);
        __syncthreads();
    }

    // C/D layout: col = lane&15, row = (lane>>4)*4 + r
    const int orow = m0 + rb + (lane >> 4) * 4;
    const int ocol = n0 + cb + fr;
    #pragma unroll
    for (int j = 0; j < 4; j++) {
        int col = ocol + j * 16;
        float bv = bias[col];
        #pragma unroll
        for (int i = 0; i < 4; i++) {
            int rbase = orow + i * 16;
            #pragma unroll
            for (int r = 0; r < 4; r++) {
                float val = acc[i][j][r] + bv;
                size_t off = (size_t)(rbase + r) * N + col;
                if (MODE == 0)      ((bf16*)Cout)[off] = __float2bfloat16(tanhf(val));
                else if (MODE == 1) ((float*)Cout)[off] = val;
                else                ((bf16*)Cout)[off] = __float2bfloat16(val);
            }
        }
    }
}

// ---------------- masked softmax: bf16 logits -> fp32 probs ----------------
// one block per row; thread t handles 16 contiguous cols [16t, 16t+16).
// mask from ORIGINAL fp32 states via SWAR packed compare (exact: int a <= wl
// <=> a <= floor(wl)).
__global__ __launch_bounds__(256)
void masked_softmax_k(const bf16* __restrict__ logitsb, float* __restrict__ out,
                      const float* __restrict__ states,
                      const unsigned* __restrict__ pact) {
    const int row  = blockIdx.x;
    const int t    = threadIdx.x;
    const int lane = t & 63, wave = t >> 6;

    __shared__ float redm[4], reds[4];
    __shared__ float smax, ssum;

    const float* wl = states + (size_t)row * SDIM + NS;
    unsigned T = 0;
    #pragma unroll
    for (int i = 0; i < 6; i++) T |= ((unsigned)(int)wl[i]) << (5 * i);
    const unsigned H  = 0x21084210u;   // guard bit (bit4) of each 5-bit field
    const unsigned TH = T | H;

    // load 16 bf16 logits (two 16B loads), unpack to fp32
    const unsigned* lrow = (const unsigned*)(logitsb + (size_t)row * NA) + t * 8;
    u32x4 raw0 = *(const u32x4*)lrow;
    u32x4 raw1 = *(const u32x4*)(lrow + 4);
    unsigned rw[8];
    #pragma unroll
    for (int i = 0; i < 4; i++) { rw[i] = raw0[i]; rw[4 + i] = raw1[i]; }

    float v[16];
    #pragma unroll
    for (int i = 0; i < 8; i++) {
        v[2 * i]     = __uint_as_float(rw[i] << 16);
        v[2 * i + 1] = __uint_as_float(rw[i] & 0xffff0000u);
    }

    const unsigned* prow = pact + t * 16;
    float lmax = -1e30f;
    #pragma unroll
    for (int q = 0; q < 4; q++) {
        u32x4 p = *(const u32x4*)(prow + q * 4);
        #pragma unroll
        for (int e = 0; e < 4; e++) {
            int j = q * 4 + e;
            bool f = (((TH - p[e]) & H) == H);   // all fields t_i >= a_i
            float lg = v[j] + (f ? 0.0f : -20.7232658f);
            v[j] = lg;
            lmax = fmaxf(lmax, lg);
        }
    }
    #pragma unroll
    for (int o = 32; o > 0; o >>= 1) lmax = fmaxf(lmax, __shfl_down(lmax, o, 64));
    if (lane == 0) redm[wave] = lmax;
    __syncthreads();
    if (t == 0) smax = fmaxf(fmaxf(redm[0], redm[1]), fmaxf(redm[2], redm[3]));
    __syncthreads();
    const float bmax = smax;

    float s = 0.f;
    #pragma unroll
    for (int j = 0; j < 16; j++) { float ev = __expf(v[j] - bmax); v[j] = ev; s += ev; }
    #pragma unroll
    for (int o = 32; o > 0; o >>= 1) s += __shfl_down(s, o, 64);
    if (lane == 0) reds[wave] = s;
    __syncthreads();
    if (t == 0) ssum = reds[0] + reds[1] + reds[2] + reds[3];
    __syncthreads();
    const float inv = 1.0f / ssum;

    float* orow = out + (size_t)row * NA + t * 16;
    #pragma unroll
    for (int q = 0; q < 4; q++) {
        f32x4 o4 = { v[q * 4] * inv, v[q * 4 + 1] * inv,
                     v[q * 4 + 2] * inv, v[q * 4 + 3] * inv };
        *(f32x4*)(orow + q * 4) = o4;
    }
}

// ---------------- launch ----------------
extern "C" void kernel_launch(void* const* d_in, const int* in_sizes, int n_in,
                              void* d_out, int out_size, void* d_ws, size_t ws_size,
                              hipStream_t stream) {
    const float* states = (const float*)d_in[0];
    const float* W1 = (const float*)d_in[1];
    const float* b1 = (const float*)d_in[2];
    const float* W2 = (const float*)d_in[3];
    const float* b2 = (const float*)d_in[4];
    const float* Wh = (const float*)d_in[5];
    const float* bh = (const float*)d_in[6];
    const int*   act = (const int*)d_in[7];
    float* out = (float*)d_out;

    char* ws = (char*)d_ws;
    bf16* statesb = (bf16*)ws; ws += (size_t)BATCH * KPAD * 2;
    bf16* w1bt    = (bf16*)ws; ws += (size_t)HID * KPAD * 2;
    bf16* w2bt    = (bf16*)ws; ws += (size_t)HID * HID * 2;
    bf16* whbt    = (bf16*)ws; ws += (size_t)NA * HID * 2;
    bf16* h1      = (bf16*)ws; ws += (size_t)BATCH * HID * 2;
    bf16* h2      = (bf16*)ws; ws += (size_t)BATCH * HID * 2;
    bf16* logitsb = (bf16*)ws; ws += (size_t)BATCH * NA * 2;
    unsigned* pact = (unsigned*)ws; ws += (size_t)NA * 4;

    dim3 tb(32, 8);
    cvt_states_k<<<(BATCH * KPAD) / 256, 256, 0, stream>>>(states, statesb);
    transpose_cvt_k<<<dim3(HID / 32, KPAD / 32), tb, 0, stream>>>(W1, w1bt, SDIM, HID, KPAD);
    transpose_cvt_k<<<dim3(HID / 32, HID / 32), tb, 0, stream>>>(W2, w2bt, HID, HID, HID);
    transpose_cvt_k<<<dim3(NA / 32, HID / 32), tb, 0, stream>>>(Wh, whbt, HID, NA, HID);
    pack_act_k<<<NA / 256, 256, 0, stream>>>(act, pact);

    gemm128<0><<<dim3(HID / 128, BATCH / 128), 256, 0, stream>>>(statesb, w1bt, b1, h1, BATCH, HID, KPAD);
    gemm128<0><<<dim3(HID / 128, BATCH / 128), 256, 0, stream>>>(h1, w2bt, b2, h2, BATCH, HID, HID);
    gemm128<2><<<dim3(NA / 128, BATCH / 128), 256, 0, stream>>>(h2, whbt, bh, logitsb, BATCH, NA, HID);

    masked_softmax_k<<<BATCH, 256, 0, stream>>>(logitsb, out, states, pact);
}

// Round 4
// 337.607 us; speedup vs baseline: 1.0471x; 1.0471x over previous
//
#include <hip/hip_runtime.h>
#include <hip/hip_bf16.h>
#include <math.h>

using bf16 = __hip_bfloat16;
typedef __attribute__((ext_vector_type(8))) short short8;
typedef __attribute__((ext_vector_type(4))) float f32x4;
typedef __attribute__((ext_vector_type(4))) unsigned int u32x4;

#define BATCH 8192
#define SDIM  70
#define NS    64
#define HID   1024
#define NA    4096
#define KPAD  128   // states K padded 70 -> 128 (multiple of 64 for BK=64)

// async global->LDS, 16 B per lane. LDS dest is wave-uniform base + lane*16.
__device__ __forceinline__ void gld_lds16(const bf16* g, bf16* l) {
    __builtin_amdgcn_global_load_lds(
        (const __attribute__((address_space(1))) void*)g,
        (__attribute__((address_space(3))) void*)l, 16, 0, 0);
}

// ---------------- fused prep kernel ----------------
// block ranges:
//   [0,4096)      : states fp32[8192][70] -> bf16[8192][128] zero-padded
//   [4096,4224)   : W1 [70][1024]   -> w1bt [1024][128]
//   [4224,5248)   : W2 [1024][1024] -> w2bt [1024][1024]
//   [5248,9344)   : Wh [1024][4096] -> whbt [4096][1024]
//   [9344,9360)   : pact (5-bit x6 SWAR pack of action_space)
__device__ __forceinline__ void tr32(const float* __restrict__ in, bf16* __restrict__ out,
                                     int K, int N, int Kpad, int bx, int by, int t,
                                     float (*tile)[33]) {
    int kb = by * 32, nb = bx * 32;
    int tx = t & 31, ty = t >> 5;
    #pragma unroll
    for (int i = 0; i < 32; i += 8) {
        int k = kb + ty + i, n = nb + tx;
        tile[ty + i][tx] = (k < K) ? in[(size_t)k * N + n] : 0.0f;
    }
    __syncthreads();
    #pragma unroll
    for (int i = 0; i < 32; i += 8) {
        int n = nb + ty + i, k = kb + tx;
        if (k < Kpad) out[(size_t)n * Kpad + k] = __float2bfloat16(tile[tx][ty + i]);
    }
}

__global__ __launch_bounds__(256)
void prep_k(const float* __restrict__ states, const float* __restrict__ W1,
            const float* __restrict__ W2, const float* __restrict__ Wh,
            const int* __restrict__ act,
            bf16* __restrict__ statesb, bf16* __restrict__ w1bt,
            bf16* __restrict__ w2bt, bf16* __restrict__ whbt,
            unsigned* __restrict__ pact) {
    __shared__ float tile[32][33];
    const int b = blockIdx.x, t = threadIdx.x;
    if (b < 4096) {
        int idx = b * 256 + t;                 // over 8192*128
        int row = idx >> 7, col = idx & 127;
        float v = (col < SDIM) ? states[row * SDIM + col] : 0.0f;
        statesb[idx] = __float2bfloat16(v);
    } else if (b < 4224) {
        int r = b - 4096;                      // 32 nb x 4 kb
        tr32(W1, w1bt, SDIM, HID, KPAD, r & 31, r >> 5, t, tile);
    } else if (b < 5248) {
        int r = b - 4224;                      // 32 x 32
        tr32(W2, w2bt, HID, HID, HID, r & 31, r >> 5, t, tile);
    } else if (b < 9344) {
        int r = b - 5248;                      // 128 nb x 32 kb
        tr32(Wh, whbt, HID, NA, HID, r & 127, r >> 7, t, tile);
    } else {
        int c = (b - 9344) * 256 + t;
        if (c < NA) {
            const int* a = act + c * 6;
            unsigned p = 0;
            #pragma unroll
            for (int i = 0; i < 6; i++) p |= ((unsigned)a[i]) << (5 * i);
            pact[c] = p;
        }
    }
}

// ---------------- bf16 MFMA GEMM: 128x128 tile, BK=64, swizzled LDS ----------------
// C[M][N] = epilogue(A[M][K] @ BT[N][K]^T + bias)
// MODE 0: tanh -> bf16; MODE 1: raw -> fp32; MODE 2: raw -> bf16
// LDS layout: row r (128 B = 8 chunks of 16 B); slot c holds global k-chunk c^(r&7).
// K must be a multiple of 64.
template<int MODE>
__global__ __launch_bounds__(256)
void gemm128(const bf16* __restrict__ A, const bf16* __restrict__ BT,
             const float* __restrict__ bias, void* __restrict__ Cout,
             int M, int N, int K) {
    const int n0 = blockIdx.x * 128;
    const int m0 = blockIdx.y * 128;
    const int tid  = threadIdx.x;
    const int wave = tid >> 6;
    const int lane = tid & 63;

    __shared__ __align__(16) bf16 As[128 * 64];   // 16 KB
    __shared__ __align__(16) bf16 Bs[128 * 64];   // 16 KB

    // staging: round q, wave w -> 8-row chunk (q*4+w); lane l -> row +(l>>3),
    // LDS slot (l&7); global k-chunk (l&7)^(l>>3)  [XOR swizzle]
    const int lr = lane >> 3;                     // 0..7
    const int gk = ((lane & 7) ^ lr) * 8;         // swizzled global k offset
    const bf16* ag = A  + (size_t)(m0 + lr) * K + gk;
    const bf16* bg = BT + (size_t)(n0 + lr) * K + gk;

    f32x4 acc[4][4];
    #pragma unroll
    for (int i = 0; i < 4; i++)
        #pragma unroll
        for (int j = 0; j < 4; j++) acc[i][j] = (f32x4){0.f, 0.f, 0.f, 0.f};

    const int rb = (wave >> 1) * 64;   // wave's m block within tile
    const int cb = (wave & 1) * 64;    // wave's n block within tile
    const int fr = lane & 15;
    const int kq = lane >> 4;          // 0..3: which 8-elem chunk of the 32-k MFMA step

    for (int k0 = 0; k0 < K; k0 += 64) {
        #pragma unroll
        for (int q = 0; q < 4; q++) {
            const int ch = q * 4 + wave;          // 8-row chunk id (wave-uniform)
            gld_lds16(ag + (size_t)(ch * 8) * K + k0, &As[ch * 512]);
            gld_lds16(bg + (size_t)(ch * 8) * K + k0, &Bs[ch * 512]);
        }
        __syncthreads();

        #pragma unroll
        for (int kk = 0; kk < 2; kk++) {          // two 32-k MFMA steps
            const int cbase = kk * 4 + kq;        // global chunk index 0..7
            short8 af[4], bfr[4];
            #pragma unroll
            for (int i = 0; i < 4; i++) {
                int r = rb + i * 16 + fr;
                af[i] = *(const short8*)&As[r * 64 + ((cbase ^ (r & 7)) * 8)];
            }
            #pragma unroll
            for (int j = 0; j < 4; j++) {
                int r = cb + j * 16 + fr;
                bfr[j] = *(const short8*)&Bs[r * 64 + ((cbase ^ (r & 7)) * 8)];
            }
            #pragma unroll
            for (int i = 0; i < 4; i++)
                #pragma unroll
                for (int j = 0; j < 4; j++)
                    acc[i][j] = __builtin_amdgcn_mfma_f32_16x16x32_bf16(af[i], bfr[j], acc[i][j], 0, 0, 0);
        }
        __syncthreads();
    }

    // C/D layout: col = lane&15, row = (lane>>4)*4 + r
    const int orow = m0 + rb + (lane >> 4) * 4;
    const int ocol = n0 + cb + fr;
    #pragma unroll
    for (int j = 0; j < 4; j++) {
        int col = ocol + j * 16;
        float bv = bias[col];
        #pragma unroll
        for (int i = 0; i < 4; i++) {
            int rbase = orow + i * 16;
            #pragma unroll
            for (int r = 0; r < 4; r++) {
                float val = acc[i][j][r] + bv;
                size_t off = (size_t)(rbase + r) * N + col;
                if (MODE == 0)      ((bf16*)Cout)[off] = __float2bfloat16(tanhf(val));
                else if (MODE == 1) ((float*)Cout)[off] = val;
                else                ((bf16*)Cout)[off] = __float2bfloat16(val);
            }
        }
    }
}

// ---------------- masked softmax: bf16 logits -> fp32 probs ----------------
// one block per row; thread t handles 16 contiguous cols [16t, 16t+16).
// mask from ORIGINAL fp32 states via SWAR packed compare (exact: int a <= wl
// <=> a <= floor(wl)).
__global__ __launch_bounds__(256)
void masked_softmax_k(const bf16* __restrict__ logitsb, float* __restrict__ out,
                      const float* __restrict__ states,
                      const unsigned* __restrict__ pact) {
    const int row  = blockIdx.x;
    const int t    = threadIdx.x;
    const int lane = t & 63, wave = t >> 6;

    __shared__ float redm[4], reds[4];
    __shared__ float smax, ssum;

    const float* wl = states + (size_t)row * SDIM + NS;
    unsigned T = 0;
    #pragma unroll
    for (int i = 0; i < 6; i++) T |= ((unsigned)(int)wl[i]) << (5 * i);
    const unsigned H  = 0x21084210u;   // guard bit (bit4) of each 5-bit field
    const unsigned TH = T | H;

    // load 16 bf16 logits (two 16B loads), unpack to fp32
    const unsigned* lrow = (const unsigned*)(logitsb + (size_t)row * NA) + t * 8;
    u32x4 raw0 = *(const u32x4*)lrow;
    u32x4 raw1 = *(const u32x4*)(lrow + 4);
    unsigned rw[8];
    #pragma unroll
    for (int i = 0; i < 4; i++) { rw[i] = raw0[i]; rw[4 + i] = raw1[i]; }

    float v[16];
    #pragma unroll
    for (int i = 0; i < 8; i++) {
        v[2 * i]     = __uint_as_float(rw[i] << 16);
        v[2 * i + 1] = __uint_as_float(rw[i] & 0xffff0000u);
    }

    const unsigned* prow = pact + t * 16;
    float lmax = -1e30f;
    #pragma unroll
    for (int q = 0; q < 4; q++) {
        u32x4 p = *(const u32x4*)(prow + q * 4);
        #pragma unroll
        for (int e = 0; e < 4; e++) {
            int j = q * 4 + e;
            bool f = (((TH - p[e]) & H) == H);   // all fields t_i >= a_i
            float lg = v[j] + (f ? 0.0f : -20.7232658f);
            v[j] = lg;
            lmax = fmaxf(lmax, lg);
        }
    }
    #pragma unroll
    for (int o = 32; o > 0; o >>= 1) lmax = fmaxf(lmax, __shfl_down(lmax, o, 64));
    if (lane == 0) redm[wave] = lmax;
    __syncthreads();
    if (t == 0) smax = fmaxf(fmaxf(redm[0], redm[1]), fmaxf(redm[2], redm[3]));
    __syncthreads();
    const float bmax = smax;

    float s = 0.f;
    #pragma unroll
    for (int j = 0; j < 16; j++) { float ev = __expf(v[j] - bmax); v[j] = ev; s += ev; }
    #pragma unroll
    for (int o = 32; o > 0; o >>= 1) s += __shfl_down(s, o, 64);
    if (lane == 0) reds[wave] = s;
    __syncthreads();
    if (t == 0) ssum = reds[0] + reds[1] + reds[2] + reds[3];
    __syncthreads();
    const float inv = 1.0f / ssum;

    float* orow = out + (size_t)row * NA + t * 16;
    #pragma unroll
    for (int q = 0; q < 4; q++) {
        f32x4 o4 = { v[q * 4] * inv, v[q * 4 + 1] * inv,
                     v[q * 4 + 2] * inv, v[q * 4 + 3] * inv };
        *(f32x4*)(orow + q * 4) = o4;
    }
}

// ---------------- launch ----------------
extern "C" void kernel_launch(void* const* d_in, const int* in_sizes, int n_in,
                              void* d_out, int out_size, void* d_ws, size_t ws_size,
                              hipStream_t stream) {
    const float* states = (const float*)d_in[0];
    const float* W1 = (const float*)d_in[1];
    const float* b1 = (const float*)d_in[2];
    const float* W2 = (const float*)d_in[3];
    const float* b2 = (const float*)d_in[4];
    const float* Wh = (const float*)d_in[5];
    const float* bh = (const float*)d_in[6];
    const int*   act = (const int*)d_in[7];
    float* out = (float*)d_out;

    char* ws = (char*)d_ws;
    bf16* statesb = (bf16*)ws; ws += (size_t)BATCH * KPAD * 2;
    bf16* w1bt    = (bf16*)ws; ws += (size_t)HID * KPAD * 2;
    bf16* w2bt    = (bf16*)ws; ws += (size_t)HID * HID * 2;
    bf16* whbt    = (bf16*)ws; ws += (size_t)NA * HID * 2;
    bf16* h1      = (bf16*)ws; ws += (size_t)BATCH * HID * 2;
    bf16* h2      = (bf16*)ws; ws += (size_t)BATCH * HID * 2;
    bf16* logitsb = (bf16*)ws; ws += (size_t)BATCH * NA * 2;
    unsigned* pact = (unsigned*)ws; ws += (size_t)NA * 4;

    prep_k<<<9360, 256, 0, stream>>>(states, W1, W2, Wh, act,
                                     statesb, w1bt, w2bt, whbt, pact);

    gemm128<0><<<dim3(HID / 128, BATCH / 128), 256, 0, stream>>>(statesb, w1bt, b1, h1, BATCH, HID, KPAD);
    gemm128<0><<<dim3(HID / 128, BATCH / 128), 256, 0, stream>>>(h1, w2bt, b2, h2, BATCH, HID, HID);
    gemm128<2><<<dim3(NA / 128, BATCH / 128), 256, 0, stream>>>(h2, whbt, bh, logitsb, BATCH, NA, HID);

    masked_softmax_k<<<BATCH, 256, 0, stream>>>(logitsb, out, states, pact);
}